// Round 5
// baseline (7805.477 us; speedup 1.0000x reference)
//
#include <hip/hip_runtime.h>
#include <math.h>

#define N_PTS 16384
#define N_CLUSTERS 4096
#define KNN_K 16
#define C_IN 64
#define C_OUT 128
#define FAN_IN 67
#define N_ROWS (N_CLUSTERS * KNN_K)   // 65536
#define FPS_BLOCKS 16

typedef float vf2 __attribute__((ext_vector_type(2)));
typedef unsigned long long u64;

// ---------------------------------------------------------------------------
// init: pp[i] = |pos_i|^2 (reference op order, no FMA), zero colsum/colsumsq,
// zero the FPS cross-block mailbox (4 slots x 16 blocks).
// ---------------------------------------------------------------------------
__global__ void init_kernel(const float* __restrict__ pos, float* __restrict__ pp,
                            float* __restrict__ cz, u64* __restrict__ g_key) {
#pragma clang fp contract(off)
    int i = blockIdx.x * 256 + threadIdx.x;
    if (i < N_PTS) {
        float a = pos[i * 3 + 0], b = pos[i * 3 + 1], c = pos[i * 3 + 2];
        pp[i] = ((a * a) + (b * b)) + (c * c);
    }
    if (blockIdx.x == 0 && threadIdx.x < 256) cz[threadIdx.x] = 0.0f;
    if (blockIdx.x == 1 && threadIdx.x < 64) g_key[threadIdx.x] = 0ULL;
}

// ---------------------------------------------------------------------------
// FPS v8: MULTI-CU. 16 blocks x 256 threads (1 wave/SIMD), 4 points/thread
// as 2 float2 pairs -> 16 VGPRs of hot state (v6/v7 post-mortem: 128-VGPR
// state forced AGPR shuffling the allocator wouldn't give up; at 16 VGPRs
// the pathology is impossible by construction, and per-CU VALU work drops
// 16x).  Cross-block agreement per step via a slotted global mailbox:
//   - each block: wave-DPP u64-key reduce -> 4 wave keys -> LDS -> block key;
//     wave0 lane0 RELEASE-stores key=(f32bits<<32 | ~gidx) to g_key[slot][b].
//   - wave0 (all 64 lanes, lane reads entry lane&15) ACQUIRE-spins until all
//     16 entries nonzero (0 = sentinel; keys are never 0 since ~gidx != 0),
//     then 4-stage shfl_xor u64 max -> every block derives the SAME winner.
//   - slot rotation S=4; each block resets ITS OWN entry of slot (step+2)
//     (relaxed); the NEXT release key-store orders the reset before any
//     other block can reach that slot (acquire of our step+1 key happens
//     first) -> no stale reads, no deadlock (single monotone write/entry).
//   - winner coords: uniform readfirstlane + scalar load (pos is read-only,
//     never written -> any cache level is valid, no ordering needed).
//   - block 0 accumulates cluster ids in LDS, bulk-stores after the loop.
// Bit-exact vs reference: d = ((dx*dx)+(dy*dy))+(dz*dz) per element, no FMA
// (fp contract off); fmax/min only SELECT values (inputs >= +0: squares);
// u64 key max = (max value, then min global index) == jnp.argmax
// first-occurrence; within-thread first match via descending-j cndmask chain.
// ---------------------------------------------------------------------------
__global__ __launch_bounds__(256)
void fps_kernel(const float* __restrict__ pos, int* __restrict__ clusters,
                u64* __restrict__ g_key) {
#pragma clang fp contract(off)
    __shared__ u64 s_wkey[4];
    __shared__ unsigned int s_win;
    __shared__ int s_cluster[N_CLUSTERS];      // 16KB, used by block 0
    const int t = threadIdx.x;
    const int b = blockIdx.x;
    const int w = t >> 6, lane = t & 63;
    const int bbase = b << 10;                 // block owns [b*1024, b*1024+1024)

    vf2 ax[2], ay[2], az[2], mdv[2];
#pragma unroll
    for (int a = 0; a < 2; ++a) {
        const int g0 = bbase + t + ((2 * a) << 8);
        const int g1 = g0 + 256;
        ax[a] = (vf2){pos[g0 * 3 + 0], pos[g1 * 3 + 0]};
        ay[a] = (vf2){pos[g0 * 3 + 1], pos[g1 * 3 + 1]};
        az[a] = (vf2){pos[g0 * 3 + 2], pos[g1 * 3 + 2]};
        mdv[a] = (vf2){__builtin_inff(), __builtin_inff()};
    }
    if (b == 0 && t == 0) s_cluster[0] = 0;
    float lx = pos[0], ly = pos[1], lz = pos[2];
    __syncthreads();

// DPP pair-max stage on (hi,lo) u64 key: old=0 for masked/invalid lanes --
// key 0 never wins (lo = ~gidx != 0).  Result lands in lane 63.
#define PAIR_STAGE(CTRL, RM)                                                          \
    do {                                                                              \
        unsigned int ohi = (unsigned int)__builtin_amdgcn_update_dpp(                 \
            0, (int)hi, (CTRL), (RM), 0xF, false);                                    \
        unsigned int olo = (unsigned int)__builtin_amdgcn_update_dpp(                 \
            0, (int)lo, (CTRL), (RM), 0xF, false);                                    \
        unsigned long long cur = ((unsigned long long)hi << 32) | lo;                 \
        unsigned long long oth = ((unsigned long long)ohi << 32) | olo;               \
        if (oth > cur) { hi = ohi; lo = olo; }                                        \
    } while (0)

    for (int step = 1; step < N_CLUSTERS; ++step) {
        const int slot = step & 3;
        const vf2 lxv = (vf2){lx, lx}, lyv = (vf2){ly, ly}, lzv = (vf2){lz, lz};
        // --- min-distance update, 4 points (per-element op order identical
        //     to reference) ---
#pragma unroll
        for (int a = 0; a < 2; ++a) {
            vf2 dx = ax[a] - lxv;
            vf2 dy = ay[a] - lyv;
            vf2 dz = az[a] - lzv;
            vf2 d = ((dx * dx) + (dy * dy)) + (dz * dz);
            vf2 m;
            m.x = fminf(mdv[a].x, d.x);
            m.y = fminf(mdv[a].y, d.y);
            mdv[a] = m;
        }
        const float bv = fmaxf(fmaxf(mdv[0].x, mdv[0].y), fmaxf(mdv[1].x, mdv[1].y));
        // first-match local j (ascending j == ascending global idx)
        int bj = 3;
        bj = (mdv[1].x == bv) ? 2 : bj;
        bj = (mdv[0].y == bv) ? 1 : bj;
        bj = (mdv[0].x == bv) ? 0 : bj;
        const unsigned int gidx = (unsigned int)(bbase + t + (bj << 8));

        // --- wave64 u64-key DPP max; result lands in lane 63 ---
        unsigned int hi = __float_as_uint(bv);
        unsigned int lo = ~gidx;                 // max(~idx) == min(idx) tie-break
        PAIR_STAGE(0x111, 0xF);  // row_shr:1
        PAIR_STAGE(0x112, 0xF);  // row_shr:2
        PAIR_STAGE(0x114, 0xF);  // row_shr:4
        PAIR_STAGE(0x118, 0xF);  // row_shr:8
        PAIR_STAGE(0x142, 0xA);  // row_bcast:15 -> rows 1,3
        PAIR_STAGE(0x143, 0xC);  // row_bcast:31 -> rows 2,3
        if (lane == 63) s_wkey[w] = ((u64)hi << 32) | lo;
        __syncthreads();  // barrier1: 4 wave keys visible

        if (w == 0) {
            // block key (broadcast LDS reads, 3 u64 compares)
            u64 bkey = s_wkey[0];
            u64 k1 = s_wkey[1], k2 = s_wkey[2], k3 = s_wkey[3];
            bkey = (k1 > bkey) ? k1 : bkey;
            bkey = (k2 > bkey) ? k2 : bkey;
            bkey = (k3 > bkey) ? k3 : bkey;
            if (lane == 0)
                __hip_atomic_store(&g_key[slot * FPS_BLOCKS + b], bkey,
                                   __ATOMIC_RELEASE, __HIP_MEMORY_SCOPE_AGENT);
            // spin: lane reads entry (lane&15); exit when all 16 published
            u64 e;
            do {
                e = __hip_atomic_load(&g_key[slot * FPS_BLOCKS + (lane & 15)],
                                      __ATOMIC_ACQUIRE, __HIP_MEMORY_SCOPE_AGENT);
            } while (!__all(e != 0));
            // 16-entry u64 max via 4-stage shfl_xor (entries repeat mod 16)
#pragma unroll
            for (int m = 1; m <= 8; m <<= 1) {
                unsigned int elo = __shfl_xor((int)(unsigned int)e, m);
                unsigned int ehi = __shfl_xor((int)(unsigned int)(e >> 32), m);
                u64 o = ((u64)ehi << 32) | elo;
                e = (o > e) ? o : e;
            }
            if (lane == 0) {
                const unsigned int win = ~((unsigned int)e);
                s_win = win;
                if (b == 0) s_cluster[step] = (int)win;
                // reset own entry of slot step+2 (ordered before our next
                // release key-store; others acquire that key before reaching
                // slot step+2 -> never see stale)
                __hip_atomic_store(&g_key[((step + 2) & 3) * FPS_BLOCKS + b], 0ULL,
                                   __ATOMIC_RELAXED, __HIP_MEMORY_SCOPE_AGENT);
            }
        }
        __syncthreads();  // barrier2: s_win resolved

        const unsigned int winu =
            (unsigned int)__builtin_amdgcn_readfirstlane((int)s_win);
        lx = pos[winu * 3 + 0];
        ly = pos[winu * 3 + 1];
        lz = pos[winu * 3 + 2];
    }
#undef PAIR_STAGE

    // block 0: bulk coalesced store of the cluster list
    if (b == 0) {
        __syncthreads();
        for (int i = t; i < N_CLUSTERS; i += 256) clusters[i] = s_cluster[i];
    }
}

// ---------------------------------------------------------------------------
// kNN: one block per cluster, 256 threads. d = (qq+pp) - 2*dot (dot FMA-
// ascending like BLAS), LDS distance array per 8192-chunk, 16 argmin rounds
// per chunk (tie -> lower index == stable top_k), exact merge of 2x16.
// Only the neighbor SET matters downstream.
// ---------------------------------------------------------------------------
__global__ __launch_bounds__(256) void knn_kernel(const float* __restrict__ pos,
                                                  const float* __restrict__ pp,
                                                  const int* __restrict__ clusters,
                                                  int* __restrict__ nbr) {
#pragma clang fp contract(off)
    __shared__ float s_d[8192];
    __shared__ float s_rv[4];
    __shared__ int   s_ri[4];
    __shared__ float s_tv[32];
    __shared__ int   s_ti[32];
    const int m = blockIdx.x, t = threadIdx.x;
    const int lane = t & 63, w = t >> 6;

    const int qi = clusters[m];
    const float qx = pos[qi * 3 + 0], qy = pos[qi * 3 + 1], qz = pos[qi * 3 + 2];
    const float qq = ((qx * qx) + (qy * qy)) + (qz * qz);

    for (int chunk = 0; chunk < 2; ++chunk) {
        const int base = chunk << 13;
        __syncthreads();  // protect s_d overwrite vs previous chunk's reads
        for (int i = t; i < 8192; i += 256) {
            const int p = base + i;
            float dot = fmaf(qx, pos[p * 3 + 0], 0.0f);
            dot = fmaf(qy, pos[p * 3 + 1], dot);
            dot = fmaf(qz, pos[p * 3 + 2], dot);
            s_d[i] = (qq + pp[p]) - 2.0f * dot;
        }
        __syncthreads();
        for (int r = 0; r < KNN_K; ++r) {
            float bv = __builtin_inff();
            int   bi = 0x7fffffff;
            for (int i = t; i < 8192; i += 256) {   // i ascending per thread
                float v = s_d[i];
                if (v < bv) { bv = v; bi = i; }     // strict < keeps first
            }
#pragma unroll
            for (int off = 32; off >= 1; off >>= 1) {
                float ov = __shfl_down(bv, off);
                int   oi = __shfl_down(bi, off);
                if (ov < bv || (ov == bv && oi < bi)) { bv = ov; bi = oi; }
            }
            if (lane == 0) { s_rv[w] = bv; s_ri[w] = bi; }
            __syncthreads();
            if (t == 0) {
                float fv = s_rv[0]; int fi = s_ri[0];
#pragma unroll
                for (int ww = 1; ww < 4; ++ww) {
                    if (s_rv[ww] < fv || (s_rv[ww] == fv && s_ri[ww] < fi)) {
                        fv = s_rv[ww]; fi = s_ri[ww];
                    }
                }
                s_tv[chunk * 16 + r] = fv;
                s_ti[chunk * 16 + r] = base + fi;
                s_d[fi] = __builtin_inff();
            }
            __syncthreads();
        }
    }
    if (t == 0) {   // exact merge of two sorted-by-(v,idx) lists
        int a = 0, b = 0;
        for (int r = 0; r < KNN_K; ++r) {
            bool takeA;
            if (b >= 16) takeA = true;
            else if (a >= 16) takeA = false;
            else {
                float va = s_tv[a], vb = s_tv[16 + b];
                takeA = (va < vb) || (va == vb && s_ti[a] < s_ti[16 + b]);
            }
            nbr[m * KNN_K + r] = takeA ? s_ti[a] : s_ti[16 + b];
            if (takeA) ++a; else ++b;
        }
    }
}

// ---------------------------------------------------------------------------
// MLP: grouped[r] = [pos[n]-pos[r>>4] (quirky full-pos indexing!), x[n]],
// h = grouped @ W^T.  PASS 1: accumulate column sum/sumsq.  PASS 2:
// recompute, y = scale*h+shift, out[m,c] = relu(max_k y) (relu∘max=max∘relu),
// plus sub_pos / sub_batch.  64 rows (= 4 whole clusters) x 128 cols / block.
// ---------------------------------------------------------------------------
template <int PASS>
__global__ __launch_bounds__(256) void mlp_kernel(const float* __restrict__ x,
                                                  const float* __restrict__ pos,
                                                  const int* __restrict__ nbr,
                                                  const float* __restrict__ W,
                                                  float* __restrict__ colsum,
                                                  float* __restrict__ colsumsq,
                                                  const float* __restrict__ ss,
                                                  const int* __restrict__ clusters,
                                                  const int* __restrict__ batch,
                                                  float* __restrict__ out) {
    __shared__ __align__(16) float At[FAN_IN][68];     // [i][r], pad 68
    __shared__ __align__(16) float Wl[FAN_IN * 132];   // [i][c], pad 132
    __shared__ float red0[128], red1[128];
    __shared__ float hm[8][132];                       // pass2 half-cluster maxima
    const int tid = threadIdx.x;
    const int R0 = blockIdx.x * 64;

    // stage W transposed
    for (int idx = tid; idx < FAN_IN * 128; idx += 256) {
        int i = idx >> 7, c = idx & 127;
        Wl[i * 132 + c] = W[c * FAN_IN + i];
    }
    // stage A transposed (gather)
    {
        const int wv = tid >> 6, lane = tid & 63;
        for (int r = wv; r < 64; r += 4) {
            const int R = R0 + r;
            const int n = nbr[R];
            At[3 + lane][r] = x[n * C_IN + lane];
            if (lane < 3) {
                const int q = R >> 4;  // faithful to source: cluster ORDINAL indexes pos
                At[lane][r] = pos[n * 3 + lane] - pos[q * 3 + lane];
            }
        }
    }
    if (PASS == 1 && tid < 128) { red0[tid] = 0.0f; red1[tid] = 0.0f; }
    __syncthreads();

    const int g = tid & 31, rg = tid >> 5;
    const int c0 = g * 4, r0 = rg * 8;
    float acc[8][4];
#pragma unroll
    for (int a = 0; a < 8; ++a)
#pragma unroll
        for (int b = 0; b < 4; ++b) acc[a][b] = 0.0f;

    for (int i = 0; i < FAN_IN; ++i) {
        const float4 w4 = *(const float4*)&Wl[i * 132 + c0];
        const float4 a0 = *(const float4*)&At[i][r0];
        const float4 a1 = *(const float4*)&At[i][r0 + 4];
        const float av[8] = {a0.x, a0.y, a0.z, a0.w, a1.x, a1.y, a1.z, a1.w};
        const float wv4[4] = {w4.x, w4.y, w4.z, w4.w};
#pragma unroll
        for (int a = 0; a < 8; ++a)
#pragma unroll
            for (int b = 0; b < 4; ++b) acc[a][b] = fmaf(av[a], wv4[b], acc[a][b]);
    }

    if (PASS == 1) {
#pragma unroll
        for (int b = 0; b < 4; ++b) {
            float s = 0.0f, sq = 0.0f;
#pragma unroll
            for (int a = 0; a < 8; ++a) {
                s += acc[a][b];
                sq = fmaf(acc[a][b], acc[a][b], sq);
            }
            atomicAdd(&red0[c0 + b], s);
            atomicAdd(&red1[c0 + b], sq);
        }
        __syncthreads();
        if (tid < 128) {
            atomicAdd(&colsum[tid], red0[tid]);
            atomicAdd(&colsumsq[tid], red1[tid]);
        }
    } else {
        // rows r0..r0+7 lie in ONE cluster (half of it): reduce then combine
#pragma unroll
        for (int b = 0; b < 4; ++b) {
            const float sc = ss[c0 + b], sh = ss[128 + c0 + b];
            float mx = -__builtin_inff();
#pragma unroll
            for (int a = 0; a < 8; ++a) mx = fmaxf(mx, fmaf(sc, acc[a][b], sh));
            hm[rg][c0 + b] = mx;
        }
        __syncthreads();
        for (int o = tid; o < 512; o += 256) {
            const int cl = o >> 7, c = o & 127;
            const float v = fmaxf(hm[2 * cl][c], hm[2 * cl + 1][c]);
            const int M = blockIdx.x * 4 + cl;
            out[M * 128 + c] = fmaxf(v, 0.0f);
        }
        if (tid < 12) {
            const int cl = tid / 3, l = tid % 3;
            const int M = blockIdx.x * 4 + cl;
            out[524288 + M * 3 + l] = pos[clusters[M] * 3 + l];
        } else if (tid < 16) {
            const int M = blockIdx.x * 4 + (tid - 12);
            out[536576 + M] = (float)batch[clusters[M]];
        }
    }
}

// ---------------------------------------------------------------------------
// stats: scale/shift from column sums (biased var, like torch BN training)
// ---------------------------------------------------------------------------
__global__ void stats_kernel(const float* __restrict__ colsum,
                             const float* __restrict__ colsumsq,
                             const float* __restrict__ gamma,
                             const float* __restrict__ beta,
                             float* __restrict__ ss) {
    const int c = threadIdx.x;
    const float inv_n = 1.0f / (float)N_ROWS;
    const float mean = colsum[c] * inv_n;
    float var = colsumsq[c] * inv_n - mean * mean;
    var = fmaxf(var, 0.0f);
    const float inv = rsqrtf(var + 1e-5f);
    const float sc = gamma[c] * inv;
    ss[c] = sc;
    ss[128 + c] = beta[c] - mean * sc;
}

// ---------------------------------------------------------------------------
extern "C" void kernel_launch(void* const* d_in, const int* in_sizes, int n_in,
                              void* d_out, int out_size, void* d_ws, size_t ws_size,
                              hipStream_t stream) {
    const float* x     = (const float*)d_in[0];
    const float* pos   = (const float*)d_in[1];
    const int*   batch = (const int*)d_in[2];
    const float* W     = (const float*)d_in[3];
    const float* gamma = (const float*)d_in[4];
    const float* beta  = (const float*)d_in[5];
    float* out = (float*)d_out;
    float* wsf = (float*)d_ws;

    int*   clusters = (int*)d_ws;            // [4096]
    int*   nbr      = clusters + 4096;       // [65536]
    float* pp       = wsf + 69632;           // [16384]
    float* colsum   = wsf + 86016;           // [128]
    float* colsumsq = wsf + 86144;           // [128]
    float* ss       = wsf + 86272;           // [256]
    u64*   g_key    = (u64*)(wsf + 86528);   // [4][16] mailbox (byte ofs 346112, 8-aligned)

    init_kernel<<<dim3(64), dim3(256), 0, stream>>>(pos, pp, colsum, g_key);
    fps_kernel<<<dim3(FPS_BLOCKS), dim3(256), 0, stream>>>(pos, clusters, g_key);
    knn_kernel<<<dim3(N_CLUSTERS), dim3(256), 0, stream>>>(pos, pp, clusters, nbr);
    mlp_kernel<1><<<dim3(1024), dim3(256), 0, stream>>>(x, pos, nbr, W, colsum, colsumsq,
                                                        ss, clusters, batch, out);
    stats_kernel<<<dim3(1), dim3(128), 0, stream>>>(colsum, colsumsq, gamma, beta, ss);
    mlp_kernel<2><<<dim3(1024), dim3(256), 0, stream>>>(x, pos, nbr, W, colsum, colsumsq,
                                                        ss, clusters, batch, out);
}

// Round 6
// 6858.488 us; speedup vs baseline: 1.1381x; 1.1381x over previous
//
#include <hip/hip_runtime.h>
#include <math.h>

#define N_PTS 16384
#define N_CLUSTERS 4096
#define KNN_K 16
#define C_IN 64
#define C_OUT 128
#define FAN_IN 67
#define N_ROWS (N_CLUSTERS * KNN_K)   // 65536
#define NBINS 256

typedef float vf2 __attribute__((ext_vector_type(2)));

// ---------------------------------------------------------------------------
// init: pp[i] = |pos_i|^2 (reference op order, no FMA), zero colsum/colsumsq
// ---------------------------------------------------------------------------
__global__ void init_kernel(const float* __restrict__ pos, float* __restrict__ pp,
                            float* __restrict__ cz) {
#pragma clang fp contract(off)
    int i = blockIdx.x * 256 + threadIdx.x;
    if (i < N_PTS) {
        float a = pos[i * 3 + 0], b = pos[i * 3 + 1], c = pos[i * 3 + 2];
        pp[i] = ((a * a) + (b * b)) + (c * c);
    }
    if (blockIdx.x == 0 && threadIdx.x < 256) cz[threadIdx.x] = 0.0f;
}

// ---------------------------------------------------------------------------
// FPS v9: single block, 512 threads (8 waves), 32 pts/thread — v6 structure
// + EXACT interval pruning.  Points are x-partitioned (256-bin histogram +
// ticket placement, one-time) so each wave owns a contiguous x-slab with
// exact interval [lo,hi] (from its own loaded x's).  Per step a wave SKIPS
// its whole update iff dist(cx,[lo,hi])^2 >= wm (its current md-max, which
// the per-step DPP reduce already yields): then for every point p of the
// wave  d_p >= dx_p^2 >= idist^2 >= wm >= md_p, so min(md_p,d_p)=md_p — the
// update is the identity and register state stays exact.  (Monotone-rounding
// holds in computed f32: fl monotone; d=((dx^2+dy^2)+dz^2)>=dx^2 under RN.)
// Skipped waves publish their stale-but-exact wm to the block max; if a
// skipped wave holds the winner, its rare path recomputes thread maxima
// lazily (registers are current).  Tie-break: explicit min ORIGINAL index
// over value-matching elements (perm lookup in LDS, rare path only) ==
// jnp.argmax first-occurrence, placement-invariant.  A wrong skip-rate can
// only cost speed, never correctness (degenerates to eager v6).
// Update math unchanged from v6: d=((dx*dx)+(dy*dy))+(dz*dz), no FMA,
// fmin/fmax only select; => bit-exact winner sequence.
// ---------------------------------------------------------------------------
__global__ __launch_bounds__(512)
__attribute__((amdgpu_waves_per_eu(2, 2)))
void fps_kernel(const float* __restrict__ pos, int* __restrict__ clusters) {
#pragma clang fp contract(off)
    __shared__ unsigned short s_perm[N_PTS];   // 32KB: slot -> original index
    __shared__ int s_cluster[N_CLUSTERS];      // 16KB result accumulator
    __shared__ int s_hist[NBINS];              // histogram, then ticket base
    __shared__ __align__(16) float s_wm[8];    // per-wave md-max
    __shared__ float s_red[16];                // setup reduce scratch
    __shared__ unsigned int s_idx[4];          // winner idx, 4-slot rotation
    const int t = threadIdx.x;
    const int w = t >> 6, lane = t & 63;
    const int wbase = w << 11;                 // wave owns slots [w*2048, +2048)

    // ---- setup pass 0: global x min/max ----
    float txmin = __builtin_inff(), txmax = -__builtin_inff();
#pragma unroll
    for (int k = 0; k < 32; ++k) {
        const float xv = pos[(t + (k << 9)) * 3];
        txmin = fminf(txmin, xv);
        txmax = fmaxf(txmax, xv);
    }
#pragma unroll
    for (int off = 32; off >= 1; off >>= 1) {
        txmin = fminf(txmin, __shfl_xor(txmin, off));
        txmax = fmaxf(txmax, __shfl_xor(txmax, off));
    }
    if (lane == 0) { s_red[w] = txmin; s_red[8 + w] = txmax; }
    if (t < NBINS) s_hist[t] = 0;
    if (t < 4) s_idx[t] = 0xffffffffu;
    if (t == 0) s_cluster[0] = 0;
    __syncthreads();
    float gxmin = s_red[0], gxmax = s_red[8];
#pragma unroll
    for (int i = 1; i < 8; ++i) {
        gxmin = fminf(gxmin, s_red[i]);
        gxmax = fmaxf(gxmax, s_red[8 + i]);
    }
    const float binw = (gxmax - gxmin) * (1.0f / NBINS);
    const float binv = 1.0f / binw;

    // ---- setup pass 1: histogram ----
#pragma unroll
    for (int k = 0; k < 32; ++k) {
        const int i = t + (k << 9);
        int b = (int)((pos[i * 3] - gxmin) * binv);
        b = (b < 0) ? 0 : ((b > NBINS - 1) ? NBINS - 1 : b);
        atomicAdd(&s_hist[b], 1);
    }
    __syncthreads();
    // ---- prefix sum (serial, one-time) -> s_hist becomes ticket base ----
    if (t == 0) {
        int run = 0;
        for (int b = 0; b < NBINS; ++b) {
            const int c = s_hist[b];
            s_hist[b] = run;
            run += c;
        }
    }
    __syncthreads();
    // ---- setup pass 2: placement (bijective by tickets) ----
#pragma unroll
    for (int k = 0; k < 32; ++k) {
        const int i = t + (k << 9);
        int b = (int)((pos[i * 3] - gxmin) * binv);
        b = (b < 0) ? 0 : ((b > NBINS - 1) ? NBINS - 1 : b);
        const int dest = atomicAdd(&s_hist[b], 1);
        s_perm[dest] = (unsigned short)i;
    }
    __syncthreads();

    // ---- gather coords into registers + exact wave x-interval ----
    vf2 ax[16], ay[16], az[16], mdv[16];
    float mnx = __builtin_inff(), mxx = -__builtin_inff();
#pragma unroll
    for (int a = 0; a < 16; ++a) {
        const int s0 = wbase + (((a << 1) | 0) << 6) + lane;
        const int s1 = wbase + (((a << 1) | 1) << 6) + lane;
        const int o0 = s_perm[s0], o1 = s_perm[s1];
        ax[a] = (vf2){pos[o0 * 3 + 0], pos[o1 * 3 + 0]};
        ay[a] = (vf2){pos[o0 * 3 + 1], pos[o1 * 3 + 1]};
        az[a] = (vf2){pos[o0 * 3 + 2], pos[o1 * 3 + 2]};
        mdv[a] = (vf2){__builtin_inff(), __builtin_inff()};
        mnx = fminf(mnx, fminf(ax[a].x, ax[a].y));
        mxx = fmaxf(mxx, fmaxf(ax[a].x, ax[a].y));
    }
#pragma unroll
    for (int off = 32; off >= 1; off >>= 1) {
        mnx = fminf(mnx, __shfl_xor(mnx, off));
        mxx = fmaxf(mxx, __shfl_xor(mxx, off));
    }
    if (lane == 0) { s_red[w] = mnx; s_red[8 + w] = mxx; }
    __syncthreads();
    const float lo = s_red[w], hi = s_red[8 + w];

    float wm = __builtin_inff();               // wave's current md-max (exact)
    float lx = pos[0], ly = pos[1], lz = pos[2];

// f32 wave-max DPP stage: old=0 for invalid lanes = identity (dists >= 0).
#define VMAX_STAGE(CTRL, RM)                                                      \
    do {                                                                          \
        int o_ = __builtin_amdgcn_update_dpp(0, __float_as_int(wmr), (CTRL), (RM),\
                                             0xF, false);                         \
        wmr = fmaxf(wmr, __int_as_float(o_));                                     \
    } while (0)

    for (int step = 1; step < N_CLUSTERS; ++step) {
        // ---- exact skip test (wave-uniform) ----
        const float dm = fmaxf(fmaxf(lo - lx, lx - hi), 0.0f);
        const bool act = (dm * dm < wm);
        float bv = 0.0f;
        if (__builtin_amdgcn_readfirstlane((int)act)) {
            // --- min-distance update (op order identical to reference) ---
            vf2 bm = (vf2){0.0f, 0.0f};
            const vf2 lxv = (vf2){lx, lx}, lyv = (vf2){ly, ly}, lzv = (vf2){lz, lz};
#pragma unroll
            for (int a = 0; a < 16; ++a) {
                vf2 dx = ax[a] - lxv;
                vf2 dy = ay[a] - lyv;
                vf2 dz = az[a] - lzv;
                vf2 d = ((dx * dx) + (dy * dy)) + (dz * dz);
                vf2 m;
                m.x = fminf(mdv[a].x, d.x);
                m.y = fminf(mdv[a].y, d.y);
                mdv[a] = m;
                bm = __builtin_elementwise_max(bm, m);
            }
            bv = fmaxf(bm.x, bm.y);
            // --- wave64 f32 DPP max -> lane 63 publishes ---
            float wmr = bv;
            VMAX_STAGE(0x111, 0xF);  // row_shr:1
            VMAX_STAGE(0x112, 0xF);  // row_shr:2
            VMAX_STAGE(0x114, 0xF);  // row_shr:4
            VMAX_STAGE(0x118, 0xF);  // row_shr:8
            VMAX_STAGE(0x142, 0xA);  // row_bcast:15 -> rows 1,3
            VMAX_STAGE(0x143, 0xC);  // row_bcast:31 -> rows 2,3
            if (lane == 63) s_wm[w] = wmr;
        }
        if (t == 0) s_idx[(step + 2) & 3] = 0xffffffffu;  // rotation reset
        __syncthreads();  // barrier1: wave maxima visible

        // ---- block max from 8 per-wave values ----
        const float4 q0 = ((const float4*)s_wm)[0];
        const float4 q1 = ((const float4*)s_wm)[1];
        const float bmax = fmaxf(fmaxf(fmaxf(q0.x, q0.y), fmaxf(q0.z, q0.w)),
                                 fmaxf(fmaxf(q1.x, q1.y), fmaxf(q1.z, q1.w)));
        wm = s_wm[w];  // refresh own wm (skipped: unchanged; active: fresh)

        // ---- rare path: winner-holding wave resolves min ORIGINAL index ----
        if (wm == bmax) {
            float tbv = bv;
            if (!act) {  // skipped wave: registers current, recompute lazily
                vf2 bm2 = mdv[0];
#pragma unroll
                for (int a = 1; a < 16; ++a) bm2 = __builtin_elementwise_max(bm2, mdv[a]);
                tbv = fmaxf(bm2.x, bm2.y);
            }
            if (tbv == bmax) {
                unsigned int mi = 0xffffffffu;
#pragma unroll
                for (int a = 0; a < 16; ++a) {
                    if (mdv[a].x == bmax) {
                        const int s0 = wbase + (((a << 1) | 0) << 6) + lane;
                        const unsigned int o = s_perm[s0];
                        mi = (o < mi) ? o : mi;
                    }
                    if (mdv[a].y == bmax) {
                        const int s1 = wbase + (((a << 1) | 1) << 6) + lane;
                        const unsigned int o = s_perm[s1];
                        mi = (o < mi) ? o : mi;
                    }
                }
                if (mi != 0xffffffffu) atomicMin(&s_idx[step & 3], mi);
            }
        }
        __syncthreads();  // barrier2: winner resolved

        const unsigned int win = s_idx[step & 3];
        if (t == 0) s_cluster[step] = (int)win;
        // uniform scalar fetch of winner coords (scalar cache)
        const unsigned int winu = (unsigned int)__builtin_amdgcn_readfirstlane((int)win);
        lx = pos[winu * 3 + 0];
        ly = pos[winu * 3 + 1];
        lz = pos[winu * 3 + 2];
    }
#undef VMAX_STAGE

    // bulk coalesced store of the cluster list
    __syncthreads();
    for (int i = t; i < N_CLUSTERS; i += 512) clusters[i] = s_cluster[i];
}

// ---------------------------------------------------------------------------
// kNN: one block per cluster, 256 threads. d = (qq+pp) - 2*dot (dot FMA-
// ascending like BLAS), LDS distance array per 8192-chunk, 16 argmin rounds
// per chunk (tie -> lower index == stable top_k), exact merge of 2x16.
// Only the neighbor SET matters downstream.
// ---------------------------------------------------------------------------
__global__ __launch_bounds__(256) void knn_kernel(const float* __restrict__ pos,
                                                  const float* __restrict__ pp,
                                                  const int* __restrict__ clusters,
                                                  int* __restrict__ nbr) {
#pragma clang fp contract(off)
    __shared__ float s_d[8192];
    __shared__ float s_rv[4];
    __shared__ int   s_ri[4];
    __shared__ float s_tv[32];
    __shared__ int   s_ti[32];
    const int m = blockIdx.x, t = threadIdx.x;
    const int lane = t & 63, w = t >> 6;

    const int qi = clusters[m];
    const float qx = pos[qi * 3 + 0], qy = pos[qi * 3 + 1], qz = pos[qi * 3 + 2];
    const float qq = ((qx * qx) + (qy * qy)) + (qz * qz);

    for (int chunk = 0; chunk < 2; ++chunk) {
        const int base = chunk << 13;
        __syncthreads();  // protect s_d overwrite vs previous chunk's reads
        for (int i = t; i < 8192; i += 256) {
            const int p = base + i;
            float dot = fmaf(qx, pos[p * 3 + 0], 0.0f);
            dot = fmaf(qy, pos[p * 3 + 1], dot);
            dot = fmaf(qz, pos[p * 3 + 2], dot);
            s_d[i] = (qq + pp[p]) - 2.0f * dot;
        }
        __syncthreads();
        for (int r = 0; r < KNN_K; ++r) {
            float bv = __builtin_inff();
            int   bi = 0x7fffffff;
            for (int i = t; i < 8192; i += 256) {   // i ascending per thread
                float v = s_d[i];
                if (v < bv) { bv = v; bi = i; }     // strict < keeps first
            }
#pragma unroll
            for (int off = 32; off >= 1; off >>= 1) {
                float ov = __shfl_down(bv, off);
                int   oi = __shfl_down(bi, off);
                if (ov < bv || (ov == bv && oi < bi)) { bv = ov; bi = oi; }
            }
            if (lane == 0) { s_rv[w] = bv; s_ri[w] = bi; }
            __syncthreads();
            if (t == 0) {
                float fv = s_rv[0]; int fi = s_ri[0];
#pragma unroll
                for (int ww = 1; ww < 4; ++ww) {
                    if (s_rv[ww] < fv || (s_rv[ww] == fv && s_ri[ww] < fi)) {
                        fv = s_rv[ww]; fi = s_ri[ww];
                    }
                }
                s_tv[chunk * 16 + r] = fv;
                s_ti[chunk * 16 + r] = base + fi;
                s_d[fi] = __builtin_inff();
            }
            __syncthreads();
        }
    }
    if (t == 0) {   // exact merge of two sorted-by-(v,idx) lists
        int a = 0, b = 0;
        for (int r = 0; r < KNN_K; ++r) {
            bool takeA;
            if (b >= 16) takeA = true;
            else if (a >= 16) takeA = false;
            else {
                float va = s_tv[a], vb = s_tv[16 + b];
                takeA = (va < vb) || (va == vb && s_ti[a] < s_ti[16 + b]);
            }
            nbr[m * KNN_K + r] = takeA ? s_ti[a] : s_ti[16 + b];
            if (takeA) ++a; else ++b;
        }
    }
}

// ---------------------------------------------------------------------------
// MLP: grouped[r] = [pos[n]-pos[r>>4] (quirky full-pos indexing!), x[n]],
// h = grouped @ W^T.  PASS 1: accumulate column sum/sumsq.  PASS 2:
// recompute, y = scale*h+shift, out[m,c] = relu(max_k y) (relu∘max=max∘relu),
// plus sub_pos / sub_batch.  64 rows (= 4 whole clusters) x 128 cols / block.
// ---------------------------------------------------------------------------
template <int PASS>
__global__ __launch_bounds__(256) void mlp_kernel(const float* __restrict__ x,
                                                  const float* __restrict__ pos,
                                                  const int* __restrict__ nbr,
                                                  const float* __restrict__ W,
                                                  float* __restrict__ colsum,
                                                  float* __restrict__ colsumsq,
                                                  const float* __restrict__ ss,
                                                  const int* __restrict__ clusters,
                                                  const int* __restrict__ batch,
                                                  float* __restrict__ out) {
    __shared__ __align__(16) float At[FAN_IN][68];     // [i][r], pad 68
    __shared__ __align__(16) float Wl[FAN_IN * 132];   // [i][c], pad 132
    __shared__ float red0[128], red1[128];
    __shared__ float hm[8][132];                       // pass2 half-cluster maxima
    const int tid = threadIdx.x;
    const int R0 = blockIdx.x * 64;

    // stage W transposed
    for (int idx = tid; idx < FAN_IN * 128; idx += 256) {
        int i = idx >> 7, c = idx & 127;
        Wl[i * 132 + c] = W[c * FAN_IN + i];
    }
    // stage A transposed (gather)
    {
        const int wv = tid >> 6, lane = tid & 63;
        for (int r = wv; r < 64; r += 4) {
            const int R = R0 + r;
            const int n = nbr[R];
            At[3 + lane][r] = x[n * C_IN + lane];
            if (lane < 3) {
                const int q = R >> 4;  // faithful to source: cluster ORDINAL indexes pos
                At[lane][r] = pos[n * 3 + lane] - pos[q * 3 + lane];
            }
        }
    }
    if (PASS == 1 && tid < 128) { red0[tid] = 0.0f; red1[tid] = 0.0f; }
    __syncthreads();

    const int g = tid & 31, rg = tid >> 5;
    const int c0 = g * 4, r0 = rg * 8;
    float acc[8][4];
#pragma unroll
    for (int a = 0; a < 8; ++a)
#pragma unroll
        for (int b = 0; b < 4; ++b) acc[a][b] = 0.0f;

    for (int i = 0; i < FAN_IN; ++i) {
        const float4 w4 = *(const float4*)&Wl[i * 132 + c0];
        const float4 a0 = *(const float4*)&At[i][r0];
        const float4 a1 = *(const float4*)&At[i][r0 + 4];
        const float av[8] = {a0.x, a0.y, a0.z, a0.w, a1.x, a1.y, a1.z, a1.w};
        const float wv4[4] = {w4.x, w4.y, w4.z, w4.w};
#pragma unroll
        for (int a = 0; a < 8; ++a)
#pragma unroll
            for (int b = 0; b < 4; ++b) acc[a][b] = fmaf(av[a], wv4[b], acc[a][b]);
    }

    if (PASS == 1) {
#pragma unroll
        for (int b = 0; b < 4; ++b) {
            float s = 0.0f, sq = 0.0f;
#pragma unroll
            for (int a = 0; a < 8; ++a) {
                s += acc[a][b];
                sq = fmaf(acc[a][b], acc[a][b], sq);
            }
            atomicAdd(&red0[c0 + b], s);
            atomicAdd(&red1[c0 + b], sq);
        }
        __syncthreads();
        if (tid < 128) {
            atomicAdd(&colsum[tid], red0[tid]);
            atomicAdd(&colsumsq[tid], red1[tid]);
        }
    } else {
        // rows r0..r0+7 lie in ONE cluster (half of it): reduce then combine
#pragma unroll
        for (int b = 0; b < 4; ++b) {
            const float sc = ss[c0 + b], sh = ss[128 + c0 + b];
            float mx = -__builtin_inff();
#pragma unroll
            for (int a = 0; a < 8; ++a) mx = fmaxf(mx, fmaf(sc, acc[a][b], sh));
            hm[rg][c0 + b] = mx;
        }
        __syncthreads();
        for (int o = tid; o < 512; o += 256) {
            const int cl = o >> 7, c = o & 127;
            const float v = fmaxf(hm[2 * cl][c], hm[2 * cl + 1][c]);
            const int M = blockIdx.x * 4 + cl;
            out[M * 128 + c] = fmaxf(v, 0.0f);
        }
        if (tid < 12) {
            const int cl = tid / 3, l = tid % 3;
            const int M = blockIdx.x * 4 + cl;
            out[524288 + M * 3 + l] = pos[clusters[M] * 3 + l];
        } else if (tid < 16) {
            const int M = blockIdx.x * 4 + (tid - 12);
            out[536576 + M] = (float)batch[clusters[M]];
        }
    }
}

// ---------------------------------------------------------------------------
// stats: scale/shift from column sums (biased var, like torch BN training)
// ---------------------------------------------------------------------------
__global__ void stats_kernel(const float* __restrict__ colsum,
                             const float* __restrict__ colsumsq,
                             const float* __restrict__ gamma,
                             const float* __restrict__ beta,
                             float* __restrict__ ss) {
    const int c = threadIdx.x;
    const float inv_n = 1.0f / (float)N_ROWS;
    const float mean = colsum[c] * inv_n;
    float var = colsumsq[c] * inv_n - mean * mean;
    var = fmaxf(var, 0.0f);
    const float inv = rsqrtf(var + 1e-5f);
    const float sc = gamma[c] * inv;
    ss[c] = sc;
    ss[128 + c] = beta[c] - mean * sc;
}

// ---------------------------------------------------------------------------
extern "C" void kernel_launch(void* const* d_in, const int* in_sizes, int n_in,
                              void* d_out, int out_size, void* d_ws, size_t ws_size,
                              hipStream_t stream) {
    const float* x     = (const float*)d_in[0];
    const float* pos   = (const float*)d_in[1];
    const int*   batch = (const int*)d_in[2];
    const float* W     = (const float*)d_in[3];
    const float* gamma = (const float*)d_in[4];
    const float* beta  = (const float*)d_in[5];
    float* out = (float*)d_out;
    float* wsf = (float*)d_ws;

    int*   clusters = (int*)d_ws;            // [4096]
    int*   nbr      = clusters + 4096;       // [65536]
    float* pp       = wsf + 69632;           // [16384]
    float* colsum   = wsf + 86016;           // [128]
    float* colsumsq = wsf + 86144;           // [128]
    float* ss       = wsf + 86272;           // [256]

    init_kernel<<<dim3(64), dim3(256), 0, stream>>>(pos, pp, colsum);
    fps_kernel<<<dim3(1), dim3(512), 0, stream>>>(pos, clusters);
    knn_kernel<<<dim3(N_CLUSTERS), dim3(256), 0, stream>>>(pos, pp, clusters, nbr);
    mlp_kernel<1><<<dim3(1024), dim3(256), 0, stream>>>(x, pos, nbr, W, colsum, colsumsq,
                                                        ss, clusters, batch, out);
    stats_kernel<<<dim3(1), dim3(128), 0, stream>>>(colsum, colsumsq, gamma, beta, ss);
    mlp_kernel<2><<<dim3(1024), dim3(256), 0, stream>>>(x, pos, nbr, W, colsum, colsumsq,
                                                        ss, clusters, batch, out);
}

// Round 7
// 5030.947 us; speedup vs baseline: 1.5515x; 1.3633x over previous
//
#include <hip/hip_runtime.h>
#include <math.h>

#define N_PTS 16384
#define N_CLUSTERS 4096
#define KNN_K 16
#define C_IN 64
#define C_OUT 128
#define FAN_IN 67
#define N_ROWS (N_CLUSTERS * KNN_K)   // 65536
#define NBINS 256

typedef float vf2 __attribute__((ext_vector_type(2)));
typedef unsigned long long u64;
typedef u64 u64x2 __attribute__((ext_vector_type(2)));

// ---------------------------------------------------------------------------
// init: pp[i] = |pos_i|^2 (reference op order, no FMA), zero colsum/colsumsq
// ---------------------------------------------------------------------------
__global__ void init_kernel(const float* __restrict__ pos, float* __restrict__ pp,
                            float* __restrict__ cz) {
#pragma clang fp contract(off)
    int i = blockIdx.x * 256 + threadIdx.x;
    if (i < N_PTS) {
        float a = pos[i * 3 + 0], b = pos[i * 3 + 1], c = pos[i * 3 + 2];
        pp[i] = ((a * a) + (b * b)) + (c * c);
    }
    if (blockIdx.x == 0 && threadIdx.x < 256) cz[threadIdx.x] = 0.0f;
}

// ---------------------------------------------------------------------------
// FPS v10: single block, 512 threads (8 waves), 32 pts/thread, x-slab
// partition + EXACT interval pruning (v9, proven) + single-barrier keyed
// reduce (v6/v9 post-mortem: with pruning the step is latency-bound --
// 2 barriers + 3 LDS round-trips + rare-path perm lookups dominated).
//   - key = (f32bits(max md) << 32) | ~min_orig_idx_of_max : u64 max ==
//     (max value, tie -> min ORIGINAL index) == jnp.argmax first-occurrence.
//   - active waves recompute their key: packed update -> in-register
//     min-orig-idx recovery (oid[16] regs hold 2x16-bit original indices,
//     loaded once at setup) -> u64 DPP pair-max (v3/v8-proven stages).
//   - skipped waves: key provably unchanged (identity-update proof as v9:
//     d >= dx^2 >= dm^2 >= wm >= md under monotone RN rounding).
//   - EVERY wave writes its (cached or fresh) key each step: 1 ds_write_b64
//     (lane 63) into parity buffer s_wkey[(step+1)&1][w]; ONE barrier; all
//     threads read 8 keys (4x ds_read_b128 broadcast) + own (b64), 7-compare
//     u64 max -> winner = ~(u32)key.  No atomicMin, no rare path, no 2nd
//     barrier, no slot resets.  Parity kills the write-after-read hazard:
//     buf[p] is read in interval s and rewritten only in interval s+1.
//   - winner coords: uniform readfirstlane + scalar load (v4/v6-proven).
//   - cluster ids accumulate in LDS, bulk coalesced store at the end.
// Update math unchanged: d=((dx*dx)+(dy*dy))+(dz*dz), no FMA (contract off),
// fmin/fmax/select only -> bit-exact winner sequence vs reference.
// ---------------------------------------------------------------------------
__global__ __launch_bounds__(512)
__attribute__((amdgpu_waves_per_eu(2, 2)))
void fps_kernel(const float* __restrict__ pos, int* __restrict__ clusters) {
#pragma clang fp contract(off)
    __shared__ unsigned short s_perm[N_PTS];     // 32KB: slot -> original index
    __shared__ int s_cluster[N_CLUSTERS];        // 16KB result accumulator
    __shared__ int s_hist[NBINS];                // histogram -> ticket base
    __shared__ float s_red[16];                  // setup reduce scratch
    __shared__ __align__(16) u64 s_wkey[2][8];   // parity-buffered wave keys
    const int t = threadIdx.x;
    const int w = t >> 6, lane = t & 63;
    const int wbase = w << 11;                   // wave owns slots [w*2048,+2048)

    // ---- setup pass 0: global x min/max ----
    float txmin = __builtin_inff(), txmax = -__builtin_inff();
#pragma unroll
    for (int k = 0; k < 32; ++k) {
        const float xv = pos[(t + (k << 9)) * 3];
        txmin = fminf(txmin, xv);
        txmax = fmaxf(txmax, xv);
    }
#pragma unroll
    for (int off = 32; off >= 1; off >>= 1) {
        txmin = fminf(txmin, __shfl_xor(txmin, off));
        txmax = fmaxf(txmax, __shfl_xor(txmax, off));
    }
    if (lane == 0) { s_red[w] = txmin; s_red[8 + w] = txmax; }
    if (t < NBINS) s_hist[t] = 0;
    if (t == 0) s_cluster[0] = 0;
    __syncthreads();
    float gxmin = s_red[0], gxmax = s_red[8];
#pragma unroll
    for (int i = 1; i < 8; ++i) {
        gxmin = fminf(gxmin, s_red[i]);
        gxmax = fmaxf(gxmax, s_red[8 + i]);
    }
    const float binv = (float)NBINS / (gxmax - gxmin);

    // ---- setup pass 1: histogram ----
#pragma unroll
    for (int k = 0; k < 32; ++k) {
        const int i = t + (k << 9);
        int b = (int)((pos[i * 3] - gxmin) * binv);
        b = (b < 0) ? 0 : ((b > NBINS - 1) ? NBINS - 1 : b);
        atomicAdd(&s_hist[b], 1);
    }
    __syncthreads();
    if (t == 0) {   // serial prefix sum (one-time)
        int run = 0;
        for (int b = 0; b < NBINS; ++b) {
            const int c = s_hist[b];
            s_hist[b] = run;
            run += c;
        }
    }
    __syncthreads();
    // ---- setup pass 2: placement (bijective by tickets) ----
#pragma unroll
    for (int k = 0; k < 32; ++k) {
        const int i = t + (k << 9);
        int b = (int)((pos[i * 3] - gxmin) * binv);
        b = (b < 0) ? 0 : ((b > NBINS - 1) ? NBINS - 1 : b);
        const int dest = atomicAdd(&s_hist[b], 1);
        s_perm[dest] = (unsigned short)i;
    }
    __syncthreads();

    // ---- gather coords + packed original indices + exact wave x-interval ----
    vf2 ax[16], ay[16], az[16], mdv[16];
    unsigned int oid[16];
    float mnx = __builtin_inff(), mxx = -__builtin_inff();
#pragma unroll
    for (int a = 0; a < 16; ++a) {
        const int s0 = wbase + (((a << 1) | 0) << 6) + lane;
        const int s1 = wbase + (((a << 1) | 1) << 6) + lane;
        const unsigned int o0 = s_perm[s0], o1 = s_perm[s1];
        oid[a] = (o1 << 16) | o0;
        ax[a] = (vf2){pos[o0 * 3 + 0], pos[o1 * 3 + 0]};
        ay[a] = (vf2){pos[o0 * 3 + 1], pos[o1 * 3 + 1]};
        az[a] = (vf2){pos[o0 * 3 + 2], pos[o1 * 3 + 2]};
        mdv[a] = (vf2){__builtin_inff(), __builtin_inff()};
        mnx = fminf(mnx, fminf(ax[a].x, ax[a].y));
        mxx = fmaxf(mxx, fmaxf(ax[a].x, ax[a].y));
    }
#pragma unroll
    for (int off = 32; off >= 1; off >>= 1) {
        mnx = fminf(mnx, __shfl_xor(mnx, off));
        mxx = fmaxf(mxx, __shfl_xor(mxx, off));
    }
    if (lane == 0) { s_red[w] = mnx; s_red[8 + w] = mxx; }
    __syncthreads();
    const float lo = s_red[w], hi = s_red[8 + w];

    float lx = pos[0], ly = pos[1], lz = pos[2];
    u64 wkey = 0;   // lane63 holds the wave's cached key after each active step

// DPP pair-max on (hi_,lo_) u64 key; old=0 masked lanes never win (lo_!=0).
#define PAIR_STAGE(CTRL, RM)                                                          \
    do {                                                                              \
        unsigned int ohi = (unsigned int)__builtin_amdgcn_update_dpp(                 \
            0, (int)hi_, (CTRL), (RM), 0xF, false);                                   \
        unsigned int olo = (unsigned int)__builtin_amdgcn_update_dpp(                 \
            0, (int)lo_, (CTRL), (RM), 0xF, false);                                   \
        u64 cur = ((u64)hi_ << 32) | lo_;                                             \
        u64 oth = ((u64)ohi << 32) | olo;                                             \
        if (oth > cur) { hi_ = ohi; lo_ = olo; }                                      \
    } while (0)

// active-wave body: packed update + min-orig-idx recovery + DPP -> wkey
#define UPDATE_AND_KEY()                                                              \
    do {                                                                              \
        const vf2 lxv = (vf2){lx, lx}, lyv = (vf2){ly, ly}, lzv = (vf2){lz, lz};      \
        vf2 bm = (vf2){0.0f, 0.0f};                                                   \
        _Pragma("unroll")                                                             \
        for (int a = 0; a < 16; ++a) {                                                \
            vf2 dx = ax[a] - lxv;                                                     \
            vf2 dy = ay[a] - lyv;                                                     \
            vf2 dz = az[a] - lzv;                                                     \
            vf2 d = ((dx * dx) + (dy * dy)) + (dz * dz);                              \
            vf2 m;                                                                    \
            m.x = fminf(mdv[a].x, d.x);                                               \
            m.y = fminf(mdv[a].y, d.y);                                               \
            mdv[a] = m;                                                               \
            bm = __builtin_elementwise_max(bm, m);                                    \
        }                                                                             \
        const float bv = fmaxf(bm.x, bm.y);                                           \
        unsigned int mi = 0xffffffffu;                                                \
        _Pragma("unroll")                                                             \
        for (int a = 0; a < 16; ++a) {                                                \
            const unsigned int c0 =                                                   \
                (mdv[a].x == bv) ? (oid[a] & 0xffffu) : 0xffffffffu;                  \
            const unsigned int c1 =                                                   \
                (mdv[a].y == bv) ? (oid[a] >> 16) : 0xffffffffu;                      \
            const unsigned int cc = (c0 < c1) ? c0 : c1;                              \
            mi = (cc < mi) ? cc : mi;                                                 \
        }                                                                             \
        unsigned int hi_ = __float_as_uint(bv);                                       \
        unsigned int lo_ = ~mi;                                                       \
        PAIR_STAGE(0x111, 0xF);                                                       \
        PAIR_STAGE(0x112, 0xF);                                                       \
        PAIR_STAGE(0x114, 0xF);                                                       \
        PAIR_STAGE(0x118, 0xF);                                                       \
        PAIR_STAGE(0x142, 0xA);                                                       \
        PAIR_STAGE(0x143, 0xC);                                                       \
        wkey = ((u64)hi_ << 32) | lo_;                                                \
    } while (0)

    // ---- prologue: step-0 update vs cluster 0, publish keys to buf[1] ----
    UPDATE_AND_KEY();
    if (lane == 63) s_wkey[1][w] = wkey;
    __syncthreads();

    for (int step = 1; step < N_CLUSTERS; ++step) {
        const int p = step & 1;
        // ---- read 8 wave keys (broadcast) + own key; u64 max tree ----
        const u64x2* kp = (const u64x2*)&s_wkey[p][0];
        const u64x2 k0 = kp[0], k1 = kp[1], k2 = kp[2], k3 = kp[3];
        u64 b0 = (k0.x > k0.y) ? k0.x : k0.y;
        u64 b1 = (k1.x > k1.y) ? k1.x : k1.y;
        u64 b2 = (k2.x > k2.y) ? k2.x : k2.y;
        u64 b3 = (k3.x > k3.y) ? k3.x : k3.y;
        b0 = (b1 > b0) ? b1 : b0;
        b2 = (b3 > b2) ? b3 : b2;
        const u64 bkey = (b2 > b0) ? b2 : b0;
        const unsigned int win = ~((unsigned int)bkey);
        if (t == 0) s_cluster[step] = (int)win;

        // ---- uniform scalar fetch of winner coords ----
        const unsigned int winu =
            (unsigned int)__builtin_amdgcn_readfirstlane((int)win);
        lx = pos[winu * 3 + 0];
        ly = pos[winu * 3 + 1];
        lz = pos[winu * 3 + 2];

        // ---- exact skip test (wave-uniform; wm = own cached key's value) ----
        const u64 own = s_wkey[p][w];
        const float wm = __uint_as_float((unsigned int)(own >> 32));
        const float dm = fmaxf(fmaxf(lo - lx, lx - hi), 0.0f);
        const bool act = (dm * dm < wm);
        if (__builtin_amdgcn_readfirstlane((int)act)) UPDATE_AND_KEY();

        // ---- publish (cached or fresh) key for the NEXT step; one barrier ----
        if (lane == 63) s_wkey[p ^ 1][w] = wkey;
        __syncthreads();
    }
#undef UPDATE_AND_KEY
#undef PAIR_STAGE

    // bulk coalesced store of the cluster list
    for (int i = t; i < N_CLUSTERS; i += 512) clusters[i] = s_cluster[i];
}

// ---------------------------------------------------------------------------
// kNN: one block per cluster, 256 threads. d = (qq+pp) - 2*dot (dot FMA-
// ascending like BLAS), LDS distance array per 8192-chunk, 16 argmin rounds
// per chunk (tie -> lower index == stable top_k), exact merge of 2x16.
// Only the neighbor SET matters downstream.
// ---------------------------------------------------------------------------
__global__ __launch_bounds__(256) void knn_kernel(const float* __restrict__ pos,
                                                  const float* __restrict__ pp,
                                                  const int* __restrict__ clusters,
                                                  int* __restrict__ nbr) {
#pragma clang fp contract(off)
    __shared__ float s_d[8192];
    __shared__ float s_rv[4];
    __shared__ int   s_ri[4];
    __shared__ float s_tv[32];
    __shared__ int   s_ti[32];
    const int m = blockIdx.x, t = threadIdx.x;
    const int lane = t & 63, w = t >> 6;

    const int qi = clusters[m];
    const float qx = pos[qi * 3 + 0], qy = pos[qi * 3 + 1], qz = pos[qi * 3 + 2];
    const float qq = ((qx * qx) + (qy * qy)) + (qz * qz);

    for (int chunk = 0; chunk < 2; ++chunk) {
        const int base = chunk << 13;
        __syncthreads();  // protect s_d overwrite vs previous chunk's reads
        for (int i = t; i < 8192; i += 256) {
            const int p = base + i;
            float dot = fmaf(qx, pos[p * 3 + 0], 0.0f);
            dot = fmaf(qy, pos[p * 3 + 1], dot);
            dot = fmaf(qz, pos[p * 3 + 2], dot);
            s_d[i] = (qq + pp[p]) - 2.0f * dot;
        }
        __syncthreads();
        for (int r = 0; r < KNN_K; ++r) {
            float bv = __builtin_inff();
            int   bi = 0x7fffffff;
            for (int i = t; i < 8192; i += 256) {   // i ascending per thread
                float v = s_d[i];
                if (v < bv) { bv = v; bi = i; }     // strict < keeps first
            }
#pragma unroll
            for (int off = 32; off >= 1; off >>= 1) {
                float ov = __shfl_down(bv, off);
                int   oi = __shfl_down(bi, off);
                if (ov < bv || (ov == bv && oi < bi)) { bv = ov; bi = oi; }
            }
            if (lane == 0) { s_rv[w] = bv; s_ri[w] = bi; }
            __syncthreads();
            if (t == 0) {
                float fv = s_rv[0]; int fi = s_ri[0];
#pragma unroll
                for (int ww = 1; ww < 4; ++ww) {
                    if (s_rv[ww] < fv || (s_rv[ww] == fv && s_ri[ww] < fi)) {
                        fv = s_rv[ww]; fi = s_ri[ww];
                    }
                }
                s_tv[chunk * 16 + r] = fv;
                s_ti[chunk * 16 + r] = base + fi;
                s_d[fi] = __builtin_inff();
            }
            __syncthreads();
        }
    }
    if (t == 0) {   // exact merge of two sorted-by-(v,idx) lists
        int a = 0, b = 0;
        for (int r = 0; r < KNN_K; ++r) {
            bool takeA;
            if (b >= 16) takeA = true;
            else if (a >= 16) takeA = false;
            else {
                float va = s_tv[a], vb = s_tv[16 + b];
                takeA = (va < vb) || (va == vb && s_ti[a] < s_ti[16 + b]);
            }
            nbr[m * KNN_K + r] = takeA ? s_ti[a] : s_ti[16 + b];
            if (takeA) ++a; else ++b;
        }
    }
}

// ---------------------------------------------------------------------------
// MLP: grouped[r] = [pos[n]-pos[r>>4] (quirky full-pos indexing!), x[n]],
// h = grouped @ W^T.  PASS 1: accumulate column sum/sumsq.  PASS 2:
// recompute, y = scale*h+shift, out[m,c] = relu(max_k y) (relu∘max=max∘relu),
// plus sub_pos / sub_batch.  64 rows (= 4 whole clusters) x 128 cols / block.
// ---------------------------------------------------------------------------
template <int PASS>
__global__ __launch_bounds__(256) void mlp_kernel(const float* __restrict__ x,
                                                  const float* __restrict__ pos,
                                                  const int* __restrict__ nbr,
                                                  const float* __restrict__ W,
                                                  float* __restrict__ colsum,
                                                  float* __restrict__ colsumsq,
                                                  const float* __restrict__ ss,
                                                  const int* __restrict__ clusters,
                                                  const int* __restrict__ batch,
                                                  float* __restrict__ out) {
    __shared__ __align__(16) float At[FAN_IN][68];     // [i][r], pad 68
    __shared__ __align__(16) float Wl[FAN_IN * 132];   // [i][c], pad 132
    __shared__ float red0[128], red1[128];
    __shared__ float hm[8][132];                       // pass2 half-cluster maxima
    const int tid = threadIdx.x;
    const int R0 = blockIdx.x * 64;

    // stage W transposed
    for (int idx = tid; idx < FAN_IN * 128; idx += 256) {
        int i = idx >> 7, c = idx & 127;
        Wl[i * 132 + c] = W[c * FAN_IN + i];
    }
    // stage A transposed (gather)
    {
        const int wv = tid >> 6, lane = tid & 63;
        for (int r = wv; r < 64; r += 4) {
            const int R = R0 + r;
            const int n = nbr[R];
            At[3 + lane][r] = x[n * C_IN + lane];
            if (lane < 3) {
                const int q = R >> 4;  // faithful to source: cluster ORDINAL indexes pos
                At[lane][r] = pos[n * 3 + lane] - pos[q * 3 + lane];
            }
        }
    }
    if (PASS == 1 && tid < 128) { red0[tid] = 0.0f; red1[tid] = 0.0f; }
    __syncthreads();

    const int g = tid & 31, rg = tid >> 5;
    const int c0 = g * 4, r0 = rg * 8;
    float acc[8][4];
#pragma unroll
    for (int a = 0; a < 8; ++a)
#pragma unroll
        for (int b = 0; b < 4; ++b) acc[a][b] = 0.0f;

    for (int i = 0; i < FAN_IN; ++i) {
        const float4 w4 = *(const float4*)&Wl[i * 132 + c0];
        const float4 a0 = *(const float4*)&At[i][r0];
        const float4 a1 = *(const float4*)&At[i][r0 + 4];
        const float av[8] = {a0.x, a0.y, a0.z, a0.w, a1.x, a1.y, a1.z, a1.w};
        const float wv4[4] = {w4.x, w4.y, w4.z, w4.w};
#pragma unroll
        for (int a = 0; a < 8; ++a)
#pragma unroll
            for (int b = 0; b < 4; ++b) acc[a][b] = fmaf(av[a], wv4[b], acc[a][b]);
    }

    if (PASS == 1) {
#pragma unroll
        for (int b = 0; b < 4; ++b) {
            float s = 0.0f, sq = 0.0f;
#pragma unroll
            for (int a = 0; a < 8; ++a) {
                s += acc[a][b];
                sq = fmaf(acc[a][b], acc[a][b], sq);
            }
            atomicAdd(&red0[c0 + b], s);
            atomicAdd(&red1[c0 + b], sq);
        }
        __syncthreads();
        if (tid < 128) {
            atomicAdd(&colsum[tid], red0[tid]);
            atomicAdd(&colsumsq[tid], red1[tid]);
        }
    } else {
        // rows r0..r0+7 lie in ONE cluster (half of it): reduce then combine
#pragma unroll
        for (int b = 0; b < 4; ++b) {
            const float sc = ss[c0 + b], sh = ss[128 + c0 + b];
            float mx = -__builtin_inff();
#pragma unroll
            for (int a = 0; a < 8; ++a) mx = fmaxf(mx, fmaf(sc, acc[a][b], sh));
            hm[rg][c0 + b] = mx;
        }
        __syncthreads();
        for (int o = tid; o < 512; o += 256) {
            const int cl = o >> 7, c = o & 127;
            const float v = fmaxf(hm[2 * cl][c], hm[2 * cl + 1][c]);
            const int M = blockIdx.x * 4 + cl;
            out[M * 128 + c] = fmaxf(v, 0.0f);
        }
        if (tid < 12) {
            const int cl = tid / 3, l = tid % 3;
            const int M = blockIdx.x * 4 + cl;
            out[524288 + M * 3 + l] = pos[clusters[M] * 3 + l];
        } else if (tid < 16) {
            const int M = blockIdx.x * 4 + (tid - 12);
            out[536576 + M] = (float)batch[clusters[M]];
        }
    }
}

// ---------------------------------------------------------------------------
// stats: scale/shift from column sums (biased var, like torch BN training)
// ---------------------------------------------------------------------------
__global__ void stats_kernel(const float* __restrict__ colsum,
                             const float* __restrict__ colsumsq,
                             const float* __restrict__ gamma,
                             const float* __restrict__ beta,
                             float* __restrict__ ss) {
    const int c = threadIdx.x;
    const float inv_n = 1.0f / (float)N_ROWS;
    const float mean = colsum[c] * inv_n;
    float var = colsumsq[c] * inv_n - mean * mean;
    var = fmaxf(var, 0.0f);
    const float inv = rsqrtf(var + 1e-5f);
    const float sc = gamma[c] * inv;
    ss[c] = sc;
    ss[128 + c] = beta[c] - mean * sc;
}

// ---------------------------------------------------------------------------
extern "C" void kernel_launch(void* const* d_in, const int* in_sizes, int n_in,
                              void* d_out, int out_size, void* d_ws, size_t ws_size,
                              hipStream_t stream) {
    const float* x     = (const float*)d_in[0];
    const float* pos   = (const float*)d_in[1];
    const int*   batch = (const int*)d_in[2];
    const float* W     = (const float*)d_in[3];
    const float* gamma = (const float*)d_in[4];
    const float* beta  = (const float*)d_in[5];
    float* out = (float*)d_out;
    float* wsf = (float*)d_ws;

    int*   clusters = (int*)d_ws;            // [4096]
    int*   nbr      = clusters + 4096;       // [65536]
    float* pp       = wsf + 69632;           // [16384]
    float* colsum   = wsf + 86016;           // [128]
    float* colsumsq = wsf + 86144;           // [128]
    float* ss       = wsf + 86272;           // [256]

    init_kernel<<<dim3(64), dim3(256), 0, stream>>>(pos, pp, colsum);
    fps_kernel<<<dim3(1), dim3(512), 0, stream>>>(pos, clusters);
    knn_kernel<<<dim3(N_CLUSTERS), dim3(256), 0, stream>>>(pos, pp, clusters, nbr);
    mlp_kernel<1><<<dim3(1024), dim3(256), 0, stream>>>(x, pos, nbr, W, colsum, colsumsq,
                                                        ss, clusters, batch, out);
    stats_kernel<<<dim3(1), dim3(128), 0, stream>>>(colsum, colsumsq, gamma, beta, ss);
    mlp_kernel<2><<<dim3(1024), dim3(256), 0, stream>>>(x, pos, nbr, W, colsum, colsumsq,
                                                        ss, clusters, batch, out);
}